// Round 5
// baseline (163.591 us; speedup 1.0000x reference)
//
#include <hip/hip_runtime.h>

#define BB 32
#define SS 1024
#define EE 256

typedef float f4 __attribute__((ext_vector_type(4)));

// Prep: one block (256 thr) per batch row.
//  wave 0: inclusive cumsum of duration[b,:] into LDS (16 elems/lane + wave scan)
//  all 4 waves: scatter inverse map idx[b][t] = s for t in [cum[s-1], cum[s])
//  mels[b] = total length.
__global__ void lr_prep_kernel(const int* __restrict__ dur,
                               int* __restrict__ mels,
                               int* __restrict__ idx,
                               int max_mel) {
    __shared__ int sdur[SS];
    __shared__ int scum[SS];
    __shared__ int stot;
    const int b = blockIdx.x;
    const int tid = threadIdx.x;

    for (int j = tid; j < SS; j += 256) sdur[j] = dur[b * SS + j];
    __syncthreads();

    if (tid < 64) {                      // wave 0 does the scan
        int vals[16];
        int run = 0;
        const int base = tid * 16;
#pragma unroll
        for (int j = 0; j < 16; ++j) { run += sdur[base + j]; vals[j] = run; }
        int inc = run;
        for (int d = 1; d < 64; d <<= 1) {
            int y = __shfl_up(inc, d, 64);
            if (tid >= d) inc += y;
        }
        const int off = inc - run;
#pragma unroll
        for (int j = 0; j < 16; ++j) scum[base + j] = off + vals[j];
        if (tid == 63) stot = inc;
    }
    __syncthreads();

    int* irow = idx + (size_t)b * max_mel;
    for (int s = tid; s < SS; s += 256) {
        const int c1 = scum[s];
        const int c0 = s ? scum[s - 1] : 0;
        for (int t = c0; t < c1; ++t) irow[t] = s;   // <=7 iters, dense writes
    }
    if (tid == 0) mels[b] = stot;
}

// Gather: one wave per output row (b,t). Uniform work, chain depth 2:
// {mels[b], idx[t]} broadcast loads (independent) -> 1KB x-row load -> 1KB nt store.
__global__ void lr_gather_kernel(const float* __restrict__ x,
                                 const int* __restrict__ mels,
                                 const int* __restrict__ idx,
                                 float* __restrict__ out,
                                 float* __restrict__ mask,
                                 int max_mel) {
    const int b = blockIdx.y;
    const int wave = threadIdx.x >> 6;   // 4 waves/block
    const int lane = threadIdx.x & 63;
    const int t = blockIdx.x * 4 + wave;
    if (t >= max_mel) return;

    const int mel_len = mels[b];
    f4* orow = (f4*)(out + ((size_t)b * max_mel + t) * EE);

    if (t < mel_len) {
        const int s = idx[(size_t)b * max_mel + t];
        const f4 v = ((const f4*)(x + ((size_t)b * SS + s) * EE))[lane];
        __builtin_nontemporal_store(v, orow + lane);
        if (lane == 0) mask[(size_t)b * max_mel + t] = 0.0f;
    } else {
        const f4 z = {0.f, 0.f, 0.f, 0.f};
        __builtin_nontemporal_store(z, orow + lane);
        if (lane == 0) mask[(size_t)b * max_mel + t] = 1.0f;
    }
}

extern "C" void kernel_launch(void* const* d_in, const int* in_sizes, int n_in,
                              void* d_out, int out_size, void* d_ws, size_t ws_size,
                              hipStream_t stream) {
    const float* x   = (const float*)d_in[0];
    const int*   dur = (const int*)d_in[1];
    float* out = (float*)d_out;

    const int max_mel = out_size / (BB * (EE + 1));
    float* mask = out + (size_t)BB * max_mel * EE;

    int* mels = (int*)d_ws;                          // 32 ints
    int* idx  = mels + 64;                           // B*max_mel ints (~460 KB)

    lr_prep_kernel<<<BB, 256, 0, stream>>>(dur, mels, idx, max_mel);

    dim3 grid((max_mel + 3) / 4, BB);
    lr_gather_kernel<<<grid, 256, 0, stream>>>(x, mels, idx, out, mask, max_mel);
}

// Round 6
// 151.027 us; speedup vs baseline: 1.0832x; 1.0832x over previous
//
#include <hip/hip_runtime.h>

#define BB 32
#define SS 1024
#define EE 256

typedef float f4 __attribute__((ext_vector_type(4)));

// One wave (block of 64) per batch row: inclusive cumsum of duration[b,:].
__global__ void lr_cumsum_kernel(const int* __restrict__ dur, int* __restrict__ cum) {
    __shared__ int sdur[SS];
    const int b = blockIdx.x;
    const int lane = threadIdx.x;
    for (int j = lane; j < SS; j += 64) sdur[j] = dur[b * SS + j];
    __syncthreads();

    int vals[16];
    int run = 0;
    const int base = lane * 16;
#pragma unroll
    for (int j = 0; j < 16; ++j) { run += sdur[base + j]; vals[j] = run; }

    int inc = run;
    for (int d = 1; d < 64; d <<= 1) {
        int y = __shfl_up(inc, d, 64);
        if (lane >= d) inc += y;
    }
    const int off = inc - run;
#pragma unroll
    for (int j = 0; j < 16; ++j) cum[b * SS + base + j] = off + vals[j];
}

// Fused scatter + tail, 2 input rows per wave.
//  - rows t0,t0+1 < SS: scatter into out rows [c0,c2) with per-iter select
//    (x loads hoisted & unconditional -> issue before the cum chain resolves)
//  - rows >= mel_len: zero-fill + mask=1
// Streaming traffic is nontemporal (read-once / write-once).
__global__ void lr_fused_kernel(const float* __restrict__ x,
                                const int* __restrict__ cum,
                                float* __restrict__ out,
                                float* __restrict__ mask,
                                int max_mel) {
    const int b = blockIdx.y;
    const int wave = threadIdx.x >> 6;      // 4 waves/block
    const int lane = threadIdx.x & 63;
    const int t0 = (blockIdx.x * 4 + wave) * 2;

    const int* crow = cum + b * SS;
    const int mel_len = crow[SS - 1];
    f4* obase = (f4*)(out + (size_t)b * max_mel * EE);
    float* mrow = mask + (size_t)b * max_mel;

    if (t0 < SS) {                          // t0 even, so t0+1 < SS too
        const f4* xbase = (const f4*)(x + (size_t)b * SS * EE);
        // Hoisted, unconditional: independent of the cum loads below.
        const f4 v1 = __builtin_nontemporal_load(xbase + (size_t)t0 * (EE / 4) + lane);
        const f4 v2 = __builtin_nontemporal_load(xbase + (size_t)(t0 + 1) * (EE / 4) + lane);
        const int c0 = t0 ? crow[t0 - 1] : 0;
        const int c1 = crow[t0];
        const int c2 = crow[t0 + 1];
        for (int tt = c0; tt < c2; ++tt) {  // contiguous range for both rows
            const f4 v = (tt < c1) ? v1 : v2;
            __builtin_nontemporal_store(v, obase + (size_t)tt * (EE / 4) + lane);
        }
        if (lane < c2 - c0) mrow[c0 + lane] = 0.0f;   // one coalesced store
    }

    const f4 z = {0.f, 0.f, 0.f, 0.f};
#pragma unroll
    for (int k = 0; k < 2; ++k) {
        const int r = t0 + k;
        if (r >= mel_len && r < max_mel) {
            __builtin_nontemporal_store(z, obase + (size_t)r * (EE / 4) + lane);
            if (lane == 0) mrow[r] = 1.0f;
        }
    }
}

extern "C" void kernel_launch(void* const* d_in, const int* in_sizes, int n_in,
                              void* d_out, int out_size, void* d_ws, size_t ws_size,
                              hipStream_t stream) {
    const float* x   = (const float*)d_in[0];
    const int*   dur = (const int*)d_in[1];
    float* out = (float*)d_out;

    const int max_mel = out_size / (BB * (EE + 1));
    float* mask = out + (size_t)BB * max_mel * EE;
    int* cum = (int*)d_ws;                  // 128 KB scratch

    lr_cumsum_kernel<<<BB, 64, 0, stream>>>(dur, cum);

    const int span = (max_mel > SS) ? max_mel : SS;
    const int pairs = (span + 1) / 2;       // 2 rows per wave
    dim3 grid((pairs + 3) / 4, BB);
    lr_fused_kernel<<<grid, 256, 0, stream>>>(x, cum, out, mask, max_mel);
}